// Round 4
// baseline (132.743 us; speedup 1.0000x reference)
//
#include <hip/hip_runtime.h>
#include <hip/hip_bf16.h>
#include <math.h>

typedef __attribute__((ext_vector_type(4))) float f32x4;
typedef __attribute__((ext_vector_type(8))) __bf16 bf16x8;
typedef __attribute__((ext_vector_type(4))) __bf16 bf16x4;

#define DEVI __device__ __forceinline__

DEVI f32x4 mfma16(bf16x8 a, bf16x8 b, f32x4 c) {
  return __builtin_amdgcn_mfma_f32_16x16x32_bf16(a, b, c, 0, 0, 0);
}

// async global->LDS, 16B per lane; LDS dest = wave-uniform base + lane*16
DEVI void gload16(const void* g, void* l) {
  __builtin_amdgcn_global_load_lds(
      (const __attribute__((address_space(1))) void*)g,
      (__attribute__((address_space(3))) void*)l, 16, 0, 0);
}

DEVI float exp2a(float x) {  // single v_exp_f32 (exp2); inputs are log2-domain
  float r;
  asm("v_exp_f32 %0, %1" : "=v"(r) : "v"(x));
  return r;
}

#define LOG2E 1.4426950408889634f
#define QSCALE 0.18033688011110793f  /* 0.125 * log2(e) */

// ---------------- fused prep: x->bf16, W transposes, bias table ----------------
__global__ __launch_bounds__(256) void prep_k(
    const float* __restrict__ x, const float* __restrict__ W_attn,
    const float* __restrict__ W_proj, const float* __restrict__ bt,
    __bf16* __restrict__ xb, __bf16* __restrict__ WaT,
    __bf16* __restrict__ WpT, float* __restrict__ tbl) {
  __shared__ float tile[32][33];
  int bid = blockIdx.x;
  const int t = threadIdx.x;
  if (bid < 4096) {
    int i = (bid * 256 + t) * 4;
    float4 v = *(const float4*)&x[i];
    bf16x4 o = {(__bf16)v.x, (__bf16)v.y, (__bf16)v.z, (__bf16)v.w};
    *(bf16x4*)&xb[i] = o;
    return;
  }
  bid -= 4096;
  if (bid < 4096) {
    const float* in;
    __bf16* out;
    int Cc, bx, by;
    if (bid < 3072) {
      in = W_attn; out = WaT; Cc = 3072; bx = bid % 96; by = bid / 96;
    } else {
      int b2 = bid - 3072;
      in = W_proj; out = WpT; Cc = 1024; bx = b2 % 32; by = b2 / 32;
    }
    const int R = 1024;
    int tx = t & 31, ty = t >> 5;
    int xcol = bx * 32 + tx;
    for (int r = ty; r < 32; r += 8)
      tile[r][tx] = in[(size_t)(by * 32 + r) * Cc + xcol];
    __syncthreads();
    int xo = by * 32 + tx;
    for (int r = ty; r < 32; r += 8)
      out[(size_t)(bx * 32 + r) * R + xo] = (__bf16)tile[tx][r];
    return;
  }
  bid -= 4096;
  int idx = bid * 256 + t;  // h*2048 + rp
  int h = idx >> 11, rp = idx & 2047;
  int bucket;
  if (rp < 16) {
    bucket = rp;
  } else {
    float v = (logf((float)rp * 0.0625f) / 2.0794415416798357f) * 16.0f;
    bucket = 16 + (int)v;
    if (bucket > 31) bucket = 31;
  }
  tbl[idx] = bt[bucket * 16 + h] * LOG2E;
}

// ---------------- GEMM: C = A @ BT^T + bias ----------------
// MODE 0: QKV epilogue -> q*QSCALE -> [B,H,T,D], k [B,H,T,D], vT [B,H,D,T]
// MODE 1: fp32 out[m*N+n]
template <int MODE>
__global__ __launch_bounds__(256) void gemm_bf16(
    const __bf16* __restrict__ A, const __bf16* __restrict__ BT,
    const float* __restrict__ bias, float* __restrict__ outF,
    __bf16* __restrict__ qb, __bf16* __restrict__ kb, __bf16* __restrict__ vtb,
    int M, int N, int K) {
  __shared__ __align__(16) __bf16 lA[128 * 32];
  __shared__ __align__(16) __bf16 lB[128 * 32];
  const int t = threadIdx.x;
  const int w = t >> 6, lane = t & 63;
  const int m0 = blockIdx.x * 128, n0 = blockIdx.y * 128;
  const int wr = (w >> 1) * 64, wc = (w & 1) * 64;

  f32x4 acc[4][4] = {};

  const int rA = lane & 15;
  const int kk = (lane >> 4) * 8;

  for (int k0 = 0; k0 < K; k0 += 32) {
    __syncthreads();
#pragma unroll
    for (int r = 0; r < 2; ++r) {
      int c = r * 256 + t;
      int row = c >> 2, cc = c & 3;
      gload16(A + (size_t)(m0 + row) * K + k0 + cc * 8,
              &lA[(r * 256 + w * 64) * 8]);
      gload16(BT + (size_t)(n0 + row) * K + k0 + cc * 8,
              &lB[(r * 256 + w * 64) * 8]);
    }
    __syncthreads();
    bf16x8 af[4], bfr[4];
#pragma unroll
    for (int i = 0; i < 4; ++i)
      af[i] = *(const bf16x8*)&lA[(wr + i * 16 + rA) * 32 + kk];
#pragma unroll
    for (int j = 0; j < 4; ++j)
      bfr[j] = *(const bf16x8*)&lB[(wc + j * 16 + rA) * 32 + kk];
#pragma unroll
    for (int i = 0; i < 4; ++i)
#pragma unroll
      for (int j = 0; j < 4; ++j)
        acc[i][j] = mfma16(af[i], bfr[j], acc[i][j]);
  }

  const int colb = n0 + wc + rA;
  const int rowb = m0 + wr + (lane >> 4) * 4;
#pragma unroll
  for (int j = 0; j < 4; ++j) {
    int n = colb + j * 16;
    float bv = bias[n];
#pragma unroll
    for (int i = 0; i < 4; ++i) {
#pragma unroll
      for (int e = 0; e < 4; ++e) {
        int m = rowb + i * 16 + e;
        float v = acc[i][j][e] + bv;
        if constexpr (MODE == 0) {
          int b = m >> 11, tt = m & 2047;
          int sec = n >> 10, nn = n & 1023;
          int h = nn >> 6, d = nn & 63;
          if (sec == 0)
            qb[(((size_t)(b * 16 + h)) * 2048 + tt) * 64 + d] = (__bf16)(v * QSCALE);
          else if (sec == 1)
            kb[(((size_t)(b * 16 + h)) * 2048 + tt) * 64 + d] = (__bf16)v;
          else
            vtb[(((size_t)(b * 16 + h)) * 64 + d) * 2048 + tt] = (__bf16)v;
        } else {
          outF[(size_t)m * N + n] = v;
        }
      }
    }
  }
}

// ---------------- flash attention (S^T, 8-wave QBLK=128, dbuf) ----------------
// grid.x = b*16+h (32), grid.y reversed 128-row q-block (16), 512 thr = 8 waves.
// Wave w owns q-rows qt2*128 + w*16 .. +16. K/V 64x64 tiles double-buffered.
// rel = 4*(2*qt2 - jt) + w : quarter fn<rel full, fn==rel diag-masked,
// fn>rel zero, rel<0 wave idle (barriers only).
__global__ __launch_bounds__(512) void attn_k(
    const __bf16* __restrict__ q, const __bf16* __restrict__ k,
    const __bf16* __restrict__ vt, const float* __restrict__ tbl,
    __bf16* __restrict__ y) {
  __shared__ __align__(16) __bf16 lK[2][64 * 64];   // [key][d], swizzled
  __shared__ __align__(16) __bf16 lV[2][64 * 64];   // [d][key], swizzled
  __shared__ __align__(16) __bf16 lPT[8][16 * 64];  // per-wave [qrow][key], swz
  __shared__ float lb[2][192];

  const int t = threadIdx.x, w = t >> 6, lane = t & 63;
  const int bh = blockIdx.x, b = bh >> 4, h = bh & 15;
  const int qt2 = (gridDim.y - 1) - blockIdx.y;   // longest blocks first
  const int qbase = qt2 * 128 + w * 16;
  const int kq = lane >> 4, ncol = lane & 15;
  const int sw = (ncol & 7);                      // row&7 for all frag rows

  const __bf16* qp = q + (size_t)bh * 2048 * 64;
  const __bf16* kp = k + (size_t)bh * 2048 * 64;
  const __bf16* vp = vt + (size_t)bh * 64 * 2048;
  const float* tb = tbl + h * 2048;
  const float bconst = tb[2047];   // bucket-31 bias (all rp >= 113)

  // Q B-fragment: lane holds Q[qbase+ncol][kq*8 + j (+32)]
  bf16x8 qf0 = *(const bf16x8*)&qp[(size_t)(qbase + ncol) * 64 + kq * 8];
  bf16x8 qf1 = *(const bf16x8*)&qp[(size_t)(qbase + ncol) * 64 + kq * 8 + 32];

  f32x4 O[4] = {};
  float m = -INFINITY, lsum = 0.f;
  __bf16* Pw = &lPT[w][0];

  const int srow = t >> 3, scc = t & 7;
  const int ssc = scc ^ (srow & 7);   // pre-swizzled source chunk

  auto STAGE = [&](int buf, int jt) {
    gload16(kp + (size_t)(jt * 64 + srow) * 64 + ssc * 8, &lK[buf][w * 512]);
    gload16(vp + (size_t)srow * 2048 + jt * 64 + ssc * 8, &lV[buf][w * 512]);
    int dtb = 2 * qt2 - jt;
    if (dtb < 3 && t < 192) {  // bias window only near the diagonal
      int rb = dtb * 64 - 63 + t;
      lb[buf][t] = tb[rb < 0 ? 0 : rb];
    }
  };

  const int jtmax = 2 * qt2 + 1;
  STAGE(0, 0);
  int cur = 0;
  for (int jt = 0; jt <= jtmax; ++jt, cur ^= 1) {
    const int dtb = 2 * qt2 - jt;
    const int rel = 4 * dtb + w;
    __syncthreads();                        // drains vmcnt: buf[cur] ready
    if (jt < jtmax) STAGE(cur ^ 1, jt + 1); // prefetch next tile
    if (rel < 0) continue;                  // wave fully masked this tile

    const __bf16* Kc = lK[cur];
    const float* lbc = lb[cur];
    const bool useb = (dtb >= 3);

    // S^T = K Q^T + bias(C-init); lane elem (fn,i): key=16fn+4kq+i, qrow=ncol
    float pv[4][4];
    const int idxb = 63 + w * 16 + ncol - 4 * kq;
    float tm = -INFINITY;
#pragma unroll
    for (int fn = 0; fn < 4; ++fn) {
      if (fn <= rel) {
        f32x4 s;
        if (useb) {
          s = (f32x4){bconst, bconst, bconst, bconst};
        } else {
#pragma unroll
          for (int i = 0; i < 4; ++i) s[i] = lbc[idxb - fn * 16 - i];
          if (fn == rel) {
#pragma unroll
            for (int i = 0; i < 4; ++i)
              if (ncol - 4 * kq - i < 0) s[i] = -1e30f;
          }
        }
        int row = fn * 16 + ncol;
        bf16x8 kf0 = *(const bf16x8*)((const char*)Kc + row * 128 + ((kq ^ sw) * 16));
        bf16x8 kf1 = *(const bf16x8*)((const char*)Kc + row * 128 + (((4 + kq) ^ sw) * 16));
        s = mfma16(kf0, qf0, s);
        s = mfma16(kf1, qf1, s);
#pragma unroll
        for (int i = 0; i < 4; ++i) {
          pv[fn][i] = s[i];
          tm = fmaxf(tm, s[i]);
        }
      }
    }
    // row max across the 4 quarters holding this row's other keys
    tm = fmaxf(tm, __shfl_xor(tm, 16));
    tm = fmaxf(tm, __shfl_xor(tm, 32));

    if (__any(tm > m + 8.f)) {   // defer-max: rescale only on real growth
      float mn = fmaxf(m, tm);
      float corr = exp2a(m - mn);   // first tile: exp2(-inf)=0
      m = mn;
      lsum *= corr;
#pragma unroll
      for (int i = 0; i < 4; ++i) {
        float ci = __shfl(corr, 4 * kq + i);   // corr of row 4kq+i
#pragma unroll
        for (int fd = 0; fd < 4; ++fd) O[fd][i] *= ci;
      }
    }

    // P = exp2(S - m) -> bf16 -> transposed LDS [qrow][key] (swizzled)
#pragma unroll
    for (int fn = 0; fn < 4; ++fn) {
      bf16x4 pb;
      if (fn <= rel) {
#pragma unroll
        for (int i = 0; i < 4; ++i) {
          float p = exp2a(pv[fn][i] - m);
          lsum += p;
          pb[i] = (__bf16)p;
        }
      } else {
        pb = (bf16x4){(__bf16)0.f, (__bf16)0.f, (__bf16)0.f, (__bf16)0.f};
      }
      *(bf16x4*)((char*)Pw + ncol * 128 + ((32 * fn + 8 * kq) ^ (sw << 4))) = pb;
    }
    asm volatile("s_waitcnt lgkmcnt(0)" ::: "memory");
    __builtin_amdgcn_sched_barrier(0);

    // O += P V : A-frag P[qrow=ncol][key], B-frag V[key][d] from lV (V^T rows)
    const __bf16* Vc = lV[cur];
    const int kf2max = (rel >= 2) ? 2 : 1;   // keys>=32 all zero if rel<2
    for (int kf2 = 0; kf2 < kf2max; ++kf2) {
      bf16x8 pf = *(const bf16x8*)((const char*)Pw + ncol * 128 +
                                   (((4 * kf2 + kq) ^ sw) * 16));
#pragma unroll
      for (int fd = 0; fd < 4; ++fd) {
        int vrow = fd * 16 + ncol;
        bf16x8 vf = *(const bf16x8*)((const char*)Vc + vrow * 128 +
                                     (((4 * kf2 + kq) ^ sw) * 16));
        O[fd] = mfma16(pf, vf, O[fd]);
      }
    }
  }

  // epilogue: total row sums, then normalize rows 4kq+i
  lsum += __shfl_xor(lsum, 16);
  lsum += __shfl_xor(lsum, 32);
#pragma unroll
  for (int i = 0; i < 4; ++i) {
    float li = __shfl(lsum, 4 * kq + i);
    float rinv = 1.0f / li;
    int row = qbase + 4 * kq + i;
#pragma unroll
    for (int fd = 0; fd < 4; ++fd) {
      int col = h * 64 + fd * 16 + ncol;
      y[((size_t)(b * 2048 + row)) * 1024 + col] = (__bf16)(O[fd][i] * rinv);
    }
  }
}

// ---------------- launch ----------------

extern "C" void kernel_launch(void* const* d_in, const int* in_sizes, int n_in,
                              void* d_out, int out_size, void* d_ws, size_t ws_size,
                              hipStream_t stream) {
  const float* x = (const float*)d_in[0];
  const float* W_attn = (const float*)d_in[1];
  const float* b_attn = (const float*)d_in[2];
  const float* W_proj = (const float*)d_in[3];
  const float* b_proj = (const float*)d_in[4];
  const float* bias_table = (const float*)d_in[5];
  float* out = (float*)d_out;

  char* ws = (char*)d_ws;
  __bf16* xb   = (__bf16*)(ws + 0);          // 4096x1024           8 MB
  __bf16* WaT  = (__bf16*)(ws + 8388608);    // 3072x1024           6 MB
  __bf16* WpT  = (__bf16*)(ws + 14680064);   // 1024x1024           2 MB
  __bf16* qb   = (__bf16*)(ws + 16777216);   // [B,H,T,D]           8 MB
  __bf16* kb   = (__bf16*)(ws + 25165824);   // [B,H,T,D]           8 MB
  __bf16* vtb  = (__bf16*)(ws + 33554432);   // [B,H,D,T]           8 MB
  __bf16* yb   = (__bf16*)(ws + 41943040);   // [B,T,C]             8 MB
  float*  tbl  = (float*)(ws + 50331648);    // [H,T] bias*log2e  128 KB

  prep_k<<<8320, 256, 0, stream>>>(x, W_attn, W_proj, bias_table,
                                   xb, WaT, WpT, tbl);
  gemm_bf16<0><<<dim3(32, 24), 256, 0, stream>>>(xb, WaT, b_attn, nullptr,
                                                 qb, kb, vtb, 4096, 3072, 1024);
  attn_k<<<dim3(32, 16), 512, 0, stream>>>(qb, kb, vtb, tbl, yb);
  gemm_bf16<1><<<dim3(32, 8), 256, 0, stream>>>(yb, WpT, b_proj, out,
                                                nullptr, nullptr, nullptr,
                                                4096, 1024, 1024);
}

// Round 5
// 124.532 us; speedup vs baseline: 1.0659x; 1.0659x over previous
//
#include <hip/hip_runtime.h>
#include <hip/hip_bf16.h>
#include <math.h>

typedef __attribute__((ext_vector_type(4))) float f32x4;
typedef __attribute__((ext_vector_type(8))) __bf16 bf16x8;
typedef __attribute__((ext_vector_type(4))) __bf16 bf16x4;

#define DEVI __device__ __forceinline__

DEVI f32x4 mfma16(bf16x8 a, bf16x8 b, f32x4 c) {
  return __builtin_amdgcn_mfma_f32_16x16x32_bf16(a, b, c, 0, 0, 0);
}

// async global->LDS, 16B per lane; LDS dest = wave-uniform base + lane*16
DEVI void gload16(const void* g, void* l) {
  __builtin_amdgcn_global_load_lds(
      (const __attribute__((address_space(1))) void*)g,
      (__attribute__((address_space(3))) void*)l, 16, 0, 0);
}

DEVI float exp2a(float x) {  // single v_exp_f32 (exp2); inputs are log2-domain
  float r;
  asm("v_exp_f32 %0, %1" : "=v"(r) : "v"(x));
  return r;
}

#define LOG2E 1.4426950408889634f
#define QSCALE 0.18033688011110793f  /* 0.125 * log2(e) */
#define FIXMAX 8.0f  /* fixed softmax shift: S<<8 always; ratio O/lsum exact */

// ---------------- fused prep: x->bf16, W transposes, bias table ----------------
__global__ __launch_bounds__(256) void prep_k(
    const float* __restrict__ x, const float* __restrict__ W_attn,
    const float* __restrict__ W_proj, const float* __restrict__ bt,
    __bf16* __restrict__ xb, __bf16* __restrict__ WaT,
    __bf16* __restrict__ WpT, float* __restrict__ tbl) {
  __shared__ float tile[32][33];
  int bid = blockIdx.x;
  const int t = threadIdx.x;
  if (bid < 4096) {
    int i = (bid * 256 + t) * 4;
    float4 v = *(const float4*)&x[i];
    bf16x4 o = {(__bf16)v.x, (__bf16)v.y, (__bf16)v.z, (__bf16)v.w};
    *(bf16x4*)&xb[i] = o;
    return;
  }
  bid -= 4096;
  if (bid < 4096) {
    const float* in;
    __bf16* out;
    int Cc, bx, by;
    if (bid < 3072) {
      in = W_attn; out = WaT; Cc = 3072; bx = bid % 96; by = bid / 96;
    } else {
      int b2 = bid - 3072;
      in = W_proj; out = WpT; Cc = 1024; bx = b2 % 32; by = b2 / 32;
    }
    const int R = 1024;
    int tx = t & 31, ty = t >> 5;
    int xcol = bx * 32 + tx;
    for (int r = ty; r < 32; r += 8)
      tile[r][tx] = in[(size_t)(by * 32 + r) * Cc + xcol];
    __syncthreads();
    int xo = by * 32 + tx;
    for (int r = ty; r < 32; r += 8)
      out[(size_t)(bx * 32 + r) * R + xo] = (__bf16)tile[tx][r];
    return;
  }
  bid -= 4096;
  int idx = bid * 256 + t;  // h*2048 + rp
  int h = idx >> 11, rp = idx & 2047;
  int bucket;
  if (rp < 16) {
    bucket = rp;
  } else {
    float v = (logf((float)rp * 0.0625f) / 2.0794415416798357f) * 16.0f;
    bucket = 16 + (int)v;
    if (bucket > 31) bucket = 31;
  }
  tbl[idx] = bt[bucket * 16 + h] * LOG2E;
}

// ---------------- GEMM: C = A @ BT^T + bias (2-phase dbuf) ----------------
// MODE 0: QKV epilogue -> q*QSCALE -> [B,H,T,D], k [B,H,T,D], vT [B,H,D,T]
// MODE 1: fp32 out[m*N+n]
template <int MODE>
__global__ __launch_bounds__(256) void gemm_bf16(
    const __bf16* __restrict__ A, const __bf16* __restrict__ BT,
    const float* __restrict__ bias, float* __restrict__ outF,
    __bf16* __restrict__ qb, __bf16* __restrict__ kb, __bf16* __restrict__ vtb,
    int M, int N, int K) {
  __shared__ __align__(16) __bf16 lA[2][128 * 32];
  __shared__ __align__(16) __bf16 lB[2][128 * 32];
  const int t = threadIdx.x;
  const int w = t >> 6, lane = t & 63;
  const int m0 = blockIdx.x * 128, n0 = blockIdx.y * 128;
  const int wr = (w >> 1) * 64, wc = (w & 1) * 64;

  f32x4 acc[4][4] = {};

  const int rA = lane & 15;
  const int kk = (lane >> 4) * 8;

  auto STAGE = [&](int buf, int k0) {
#pragma unroll
    for (int r = 0; r < 2; ++r) {
      int c = r * 256 + t;
      int row = c >> 2, cc = c & 3;
      gload16(A + (size_t)(m0 + row) * K + k0 + cc * 8,
              &lA[buf][(r * 256 + w * 64) * 8]);
      gload16(BT + (size_t)(n0 + row) * K + k0 + cc * 8,
              &lB[buf][(r * 256 + w * 64) * 8]);
    }
  };

  STAGE(0, 0);
  int cur = 0;
  for (int k0 = 0; k0 < K; k0 += 32, cur ^= 1) {
    __syncthreads();                         // buf[cur] ready (vmcnt drained)
    if (k0 + 32 < K) STAGE(cur ^ 1, k0 + 32);  // prefetch flies under MFMA
    bf16x8 af[4], bfr[4];
#pragma unroll
    for (int i = 0; i < 4; ++i)
      af[i] = *(const bf16x8*)&lA[cur][(wr + i * 16 + rA) * 32 + kk];
#pragma unroll
    for (int j = 0; j < 4; ++j)
      bfr[j] = *(const bf16x8*)&lB[cur][(wc + j * 16 + rA) * 32 + kk];
#pragma unroll
    for (int i = 0; i < 4; ++i)
#pragma unroll
      for (int j = 0; j < 4; ++j)
        acc[i][j] = mfma16(af[i], bfr[j], acc[i][j]);
  }

  const int colb = n0 + wc + rA;
  const int rowb = m0 + wr + (lane >> 4) * 4;
#pragma unroll
  for (int j = 0; j < 4; ++j) {
    int n = colb + j * 16;
    float bv = bias[n];
#pragma unroll
    for (int i = 0; i < 4; ++i) {
#pragma unroll
      for (int e = 0; e < 4; ++e) {
        int m = rowb + i * 16 + e;
        float v = acc[i][j][e] + bv;
        if constexpr (MODE == 0) {
          int b = m >> 11, tt = m & 2047;
          int sec = n >> 10, nn = n & 1023;
          int h = nn >> 6, d = nn & 63;
          if (sec == 0)
            qb[(((size_t)(b * 16 + h)) * 2048 + tt) * 64 + d] = (__bf16)(v * QSCALE);
          else if (sec == 1)
            kb[(((size_t)(b * 16 + h)) * 2048 + tt) * 64 + d] = (__bf16)v;
          else
            vtb[(((size_t)(b * 16 + h)) * 64 + d) * 2048 + tt] = (__bf16)v;
        } else {
          outF[(size_t)m * N + n] = v;
        }
      }
    }
  }
}

// ---------------- flash attention (S^T, paired q-tiles, fixed-max) ----------------
// grid.x = b*16+h (32), grid.y = pair p (16); block = 4 waves, QBLK=64.
// Block processes q-tiles {31-p, p}: every block does exactly 33 tile-steps
// (perfect balance, no tail). Fixed softmax shift FIXMAX replaces max
// tracking: P = exp2(S - 8); O/lsum ratio is exact (scale cancels).
__global__ __launch_bounds__(256) void attn_k(
    const __bf16* __restrict__ q, const __bf16* __restrict__ k,
    const __bf16* __restrict__ vt, const float* __restrict__ tbl,
    __bf16* __restrict__ y) {
  __shared__ __align__(16) __bf16 lK[2][64 * 64];   // [key][d], swizzled
  __shared__ __align__(16) __bf16 lV[2][64 * 64];   // [d][key], swizzled
  __shared__ __align__(16) __bf16 lPT[4][16 * 64];  // per-wave [qrow][key], swz
  __shared__ float lb[2][128];

  const int t = threadIdx.x, w = t >> 6, lane = t & 63;
  const int bh = blockIdx.x, b = bh >> 4, h = bh & 15;
  const int p = blockIdx.y;
  const int kq = lane >> 4, ncol = lane & 15;
  const int sw = (ncol & 7);                      // row&7 for all frag rows

  const __bf16* qp = q + (size_t)bh * 2048 * 64;
  const __bf16* kp = k + (size_t)bh * 2048 * 64;
  const __bf16* vp = vt + (size_t)bh * 64 * 2048;
  const float* tb = tbl + h * 2048;
  const float bconst = tb[2047] - FIXMAX;  // bucket-31 bias, fixed shift folded

  __bf16* Pw = &lPT[w][0];

  auto STAGE = [&](int buf, int qt_, int jt_) {
#pragma unroll
    for (int r = 0; r < 2; ++r) {
      int c = r * 256 + t;
      int row = c >> 3, cc = c & 7;
      int sc = cc ^ (row & 7);   // pre-swizzled source chunk
      gload16(kp + (size_t)(jt_ * 64 + row) * 64 + sc * 8,
              &lK[buf][(r * 256 + w * 64) * 8]);
      gload16(vp + (size_t)row * 2048 + jt_ * 64 + sc * 8,
              &lV[buf][(r * 256 + w * 64) * 8]);
    }
    int dt_ = qt_ - jt_;
    if (dt_ < 3 && t < 128) {  // bias window only near the diagonal
      int rb = dt_ * 64 - 63 + t;
      lb[buf][t] = tb[rb < 0 ? 0 : rb] - FIXMAX;
    }
  };

  const int qts[2] = {31 - p, p};
  int cur = 0;
  STAGE(0, qts[0], 0);

  for (int seg = 0; seg < 2; ++seg) {
    const int qt = qts[seg];
    const int qbase = qt * 64 + w * 16;
    // Q B-fragment: lane holds Q[qbase+ncol][kq*8 + j (+32)]
    bf16x8 qf0 = *(const bf16x8*)&qp[(size_t)(qbase + ncol) * 64 + kq * 8];
    bf16x8 qf1 = *(const bf16x8*)&qp[(size_t)(qbase + ncol) * 64 + kq * 8 + 32];

    f32x4 O[4] = {};
    float lsum = 0.f;

    for (int jt = 0; jt <= qt; ++jt, cur ^= 1) {
      const int dt = qt - jt;
      const int rel = 4 * dt + w;
      __syncthreads();                       // drains vmcnt: buf[cur] ready
      if (jt < qt) STAGE(cur ^ 1, qt, jt + 1);
      else if (seg == 0) STAGE(cur ^ 1, qts[1], 0);

      const __bf16* Kc = lK[cur];
      const float* lbc = lb[cur];
      const bool useb = (dt >= 3);

      // S^T = K Q^T + (bias - FIXMAX) C-init; elem (fn,i): key=16fn+4kq+i,
      // qrow=ncol. P = exp2(S) directly (shift already folded into C-init).
      const int idxb = 63 + w * 16 + ncol - 4 * kq;
#pragma unroll
      for (int fn = 0; fn < 4; ++fn) {
        bf16x4 pb;
        if (fn <= rel) {
          f32x4 s;
          if (useb) {
            s = (f32x4){bconst, bconst, bconst, bconst};
          } else {
#pragma unroll
            for (int i = 0; i < 4; ++i) s[i] = lbc[idxb - fn * 16 - i];
            if (fn == rel) {   // diagonal quarter: mask future keys
#pragma unroll
              for (int i = 0; i < 4; ++i)
                if (ncol - 4 * kq - i < 0) s[i] = -1e30f;
            }
          }
          int row = fn * 16 + ncol;
          bf16x8 kf0 = *(const bf16x8*)((const char*)Kc + row * 128 + ((kq ^ sw) * 16));
          bf16x8 kf1 = *(const bf16x8*)((const char*)Kc + row * 128 + (((4 + kq) ^ sw) * 16));
          s = mfma16(kf0, qf0, s);
          s = mfma16(kf1, qf1, s);
#pragma unroll
          for (int i = 0; i < 4; ++i) {
            float pe = exp2a(s[i]);
            lsum += pe;
            pb[i] = (__bf16)pe;
          }
        } else {
          pb = (bf16x4){(__bf16)0.f, (__bf16)0.f, (__bf16)0.f, (__bf16)0.f};
        }
        *(bf16x4*)((char*)Pw + ncol * 128 + ((32 * fn + 8 * kq) ^ (sw << 4))) = pb;
      }
      asm volatile("s_waitcnt lgkmcnt(0)" ::: "memory");
      __builtin_amdgcn_sched_barrier(0);

      // O += P V : A-frag P[qrow=ncol][key], B-frag V[key][d] from lV rows
      const __bf16* Vc = lV[cur];
      const int kf2max = (rel >= 2) ? 2 : 1;   // keys>=32 all zero if rel<2
      for (int kf2 = 0; kf2 < kf2max; ++kf2) {
        bf16x8 pf = *(const bf16x8*)((const char*)Pw + ncol * 128 +
                                     (((4 * kf2 + kq) ^ sw) * 16));
#pragma unroll
        for (int fd = 0; fd < 4; ++fd) {
          int vrow = fd * 16 + ncol;
          bf16x8 vf = *(const bf16x8*)((const char*)Vc + vrow * 128 +
                                       (((4 * kf2 + kq) ^ sw) * 16));
          O[fd] = mfma16(pf, vf, O[fd]);
        }
      }
    }

    // epilogue: total row sums, then normalize rows 4kq+i
    float ls = lsum;
    ls += __shfl_xor(ls, 16);
    ls += __shfl_xor(ls, 32);
#pragma unroll
    for (int i = 0; i < 4; ++i) {
      float li = __shfl(ls, 4 * kq + i);
      float rinv = 1.0f / li;
      int row = qbase + 4 * kq + i;
#pragma unroll
      for (int fd = 0; fd < 4; ++fd) {
        int col = h * 64 + fd * 16 + ncol;
        y[((size_t)(b * 2048 + row)) * 1024 + col] = (__bf16)(O[fd][i] * rinv);
      }
    }
  }
}

// ---------------- launch ----------------

extern "C" void kernel_launch(void* const* d_in, const int* in_sizes, int n_in,
                              void* d_out, int out_size, void* d_ws, size_t ws_size,
                              hipStream_t stream) {
  const float* x = (const float*)d_in[0];
  const float* W_attn = (const float*)d_in[1];
  const float* b_attn = (const float*)d_in[2];
  const float* W_proj = (const float*)d_in[3];
  const float* b_proj = (const float*)d_in[4];
  const float* bias_table = (const float*)d_in[5];
  float* out = (float*)d_out;

  char* ws = (char*)d_ws;
  __bf16* xb   = (__bf16*)(ws + 0);          // 4096x1024           8 MB
  __bf16* WaT  = (__bf16*)(ws + 8388608);    // 3072x1024           6 MB
  __bf16* WpT  = (__bf16*)(ws + 14680064);   // 1024x1024           2 MB
  __bf16* qb   = (__bf16*)(ws + 16777216);   // [B,H,T,D]           8 MB
  __bf16* kb   = (__bf16*)(ws + 25165824);   // [B,H,T,D]           8 MB
  __bf16* vtb  = (__bf16*)(ws + 33554432);   // [B,H,D,T]           8 MB
  __bf16* yb   = (__bf16*)(ws + 41943040);   // [B,T,C]             8 MB
  float*  tbl  = (float*)(ws + 50331648);    // [H,T] bias*log2e  128 KB

  prep_k<<<8320, 256, 0, stream>>>(x, W_attn, W_proj, bias_table,
                                   xb, WaT, WpT, tbl);
  gemm_bf16<0><<<dim3(32, 24), 256, 0, stream>>>(xb, WaT, b_attn, nullptr,
                                                 qb, kb, vtb, 4096, 3072, 1024);
  attn_k<<<dim3(32, 16), 256, 0, stream>>>(qb, kb, vtb, tbl, yb);
  gemm_bf16<1><<<dim3(32, 8), 256, 0, stream>>>(yb, WpT, b_proj, out,
                                                nullptr, nullptr, nullptr,
                                                4096, 1024, 1024);
}

// Round 7
// 119.030 us; speedup vs baseline: 1.1152x; 1.0462x over previous
//
#include <hip/hip_runtime.h>
#include <hip/hip_bf16.h>
#include <math.h>

typedef __attribute__((ext_vector_type(4))) float f32x4;
typedef __attribute__((ext_vector_type(8))) __bf16 bf16x8;
typedef __attribute__((ext_vector_type(4))) __bf16 bf16x4;

#define DEVI __device__ __forceinline__

DEVI f32x4 mfma16(bf16x8 a, bf16x8 b, f32x4 c) {
  return __builtin_amdgcn_mfma_f32_16x16x32_bf16(a, b, c, 0, 0, 0);
}

// async global->LDS, 16B per lane; LDS dest = wave-uniform base + lane*16
DEVI void gload16(const void* g, void* l) {
  __builtin_amdgcn_global_load_lds(
      (const __attribute__((address_space(1))) void*)g,
      (__attribute__((address_space(3))) void*)l, 16, 0, 0);
}

DEVI float exp2a(float x) {  // single v_exp_f32 (exp2); inputs are log2-domain
  float r;
  asm("v_exp_f32 %0, %1" : "=v"(r) : "v"(x));
  return r;
}

#define LOG2E 1.4426950408889634f
#define QSCALE 0.18033688011110793f  /* 0.125 * log2(e) */
#define FIXMAX 8.0f  /* fixed softmax shift: S<<8 always; ratio O/lsum exact */

// ---------------- fused prep: x->bf16, W transposes, bias table ----------------
__global__ __launch_bounds__(256) void prep_k(
    const float* __restrict__ x, const float* __restrict__ W_attn,
    const float* __restrict__ W_proj, const float* __restrict__ bt,
    __bf16* __restrict__ xb, __bf16* __restrict__ WaT,
    __bf16* __restrict__ WpT, float* __restrict__ tbl) {
  __shared__ float tile[32][33];
  int bid = blockIdx.x;
  const int t = threadIdx.x;
  if (bid < 4096) {
    int i = (bid * 256 + t) * 4;
    float4 v = *(const float4*)&x[i];
    bf16x4 o = {(__bf16)v.x, (__bf16)v.y, (__bf16)v.z, (__bf16)v.w};
    *(bf16x4*)&xb[i] = o;
    return;
  }
  bid -= 4096;
  if (bid < 4096) {
    const float* in;
    __bf16* out;
    int Cc, bx, by;
    if (bid < 3072) {
      in = W_attn; out = WaT; Cc = 3072; bx = bid % 96; by = bid / 96;
    } else {
      int b2 = bid - 3072;
      in = W_proj; out = WpT; Cc = 1024; bx = b2 % 32; by = b2 / 32;
    }
    const int R = 1024;
    int tx = t & 31, ty = t >> 5;
    int xcol = bx * 32 + tx;
    for (int r = ty; r < 32; r += 8)
      tile[r][tx] = in[(size_t)(by * 32 + r) * Cc + xcol];
    __syncthreads();
    int xo = by * 32 + tx;
    for (int r = ty; r < 32; r += 8)
      out[(size_t)(bx * 32 + r) * R + xo] = (__bf16)tile[tx][r];
    return;
  }
  bid -= 4096;
  int idx = bid * 256 + t;  // h*2048 + rp
  int h = idx >> 11, rp = idx & 2047;
  int bucket;
  if (rp < 16) {
    bucket = rp;
  } else {
    float v = (logf((float)rp * 0.0625f) / 2.0794415416798357f) * 16.0f;
    bucket = 16 + (int)v;
    if (bucket > 31) bucket = 31;
  }
  tbl[idx] = bt[bucket * 16 + h] * LOG2E;
}

// ---------------- GEMM: C = A @ BT^T + bias (2-phase dbuf) ----------------
// MODE 0: QKV epilogue -> q*QSCALE -> [B,H,T,D], k [B,H,T,D], vT [B,H,D,T]
// MODE 1: fp32 out[m*N+n]
template <int MODE>
__global__ __launch_bounds__(256) void gemm_bf16(
    const __bf16* __restrict__ A, const __bf16* __restrict__ BT,
    const float* __restrict__ bias, float* __restrict__ outF,
    __bf16* __restrict__ qb, __bf16* __restrict__ kb, __bf16* __restrict__ vtb,
    int M, int N, int K) {
  __shared__ __align__(16) __bf16 lA[2][128 * 32];
  __shared__ __align__(16) __bf16 lB[2][128 * 32];
  const int t = threadIdx.x;
  const int w = t >> 6, lane = t & 63;
  const int m0 = blockIdx.x * 128, n0 = blockIdx.y * 128;
  const int wr = (w >> 1) * 64, wc = (w & 1) * 64;

  f32x4 acc[4][4] = {};

  const int rA = lane & 15;
  const int kk = (lane >> 4) * 8;

  auto STAGE = [&](int buf, int k0) {
#pragma unroll
    for (int r = 0; r < 2; ++r) {
      int c = r * 256 + t;
      int row = c >> 2, cc = c & 3;
      gload16(A + (size_t)(m0 + row) * K + k0 + cc * 8,
              &lA[buf][(r * 256 + w * 64) * 8]);
      gload16(BT + (size_t)(n0 + row) * K + k0 + cc * 8,
              &lB[buf][(r * 256 + w * 64) * 8]);
    }
  };

  STAGE(0, 0);
  int cur = 0;
  for (int k0 = 0; k0 < K; k0 += 32, cur ^= 1) {
    __syncthreads();                         // buf[cur] ready (vmcnt drained)
    if (k0 + 32 < K) STAGE(cur ^ 1, k0 + 32);  // prefetch flies under MFMA
    bf16x8 af[4], bfr[4];
#pragma unroll
    for (int i = 0; i < 4; ++i)
      af[i] = *(const bf16x8*)&lA[cur][(wr + i * 16 + rA) * 32 + kk];
#pragma unroll
    for (int j = 0; j < 4; ++j)
      bfr[j] = *(const bf16x8*)&lB[cur][(wc + j * 16 + rA) * 32 + kk];
#pragma unroll
    for (int i = 0; i < 4; ++i)
#pragma unroll
      for (int j = 0; j < 4; ++j)
        acc[i][j] = mfma16(af[i], bfr[j], acc[i][j]);
  }

  const int colb = n0 + wc + rA;
  const int rowb = m0 + wr + (lane >> 4) * 4;
#pragma unroll
  for (int j = 0; j < 4; ++j) {
    int n = colb + j * 16;
    float bv = bias[n];
#pragma unroll
    for (int i = 0; i < 4; ++i) {
#pragma unroll
      for (int e = 0; e < 4; ++e) {
        int m = rowb + i * 16 + e;
        float v = acc[i][j][e] + bv;
        if constexpr (MODE == 0) {
          int b = m >> 11, tt = m & 2047;
          int sec = n >> 10, nn = n & 1023;
          int h = nn >> 6, d = nn & 63;
          if (sec == 0)
            qb[(((size_t)(b * 16 + h)) * 2048 + tt) * 64 + d] = (__bf16)(v * QSCALE);
          else if (sec == 1)
            kb[(((size_t)(b * 16 + h)) * 2048 + tt) * 64 + d] = (__bf16)v;
          else
            vtb[(((size_t)(b * 16 + h)) * 64 + d) * 2048 + tt] = (__bf16)v;
        } else {
          outF[(size_t)m * N + n] = v;
        }
      }
    }
  }
}

// ---------------- flash attention (S^T, per-qt blocks, single-buf, fixed-max) --
// grid.x = b*16+h (32), grid.y -> qt = 31 - blockIdx.y (longest first).
// 1024 blocks of 4 waves, LDS 24.5KB -> up to 6 blocks/CU; latency hidden by
// TLP across blocks instead of intra-block dbuf. Fixed softmax shift FIXMAX:
// P = exp2(S - 8); O/lsum ratio exact (scale cancels).
__global__ __launch_bounds__(256) void attn_k(
    const __bf16* __restrict__ q, const __bf16* __restrict__ k,
    const __bf16* __restrict__ vt, const float* __restrict__ tbl,
    __bf16* __restrict__ y) {
  __shared__ __align__(16) __bf16 lK[64 * 64];      // [key][d], swizzled
  __shared__ __align__(16) __bf16 lV[64 * 64];      // [d][key], swizzled
  __shared__ __align__(16) __bf16 lPT[4][16 * 64];  // per-wave [qrow][key], swz
  __shared__ float lb[128];

  const int t = threadIdx.x, w = t >> 6, lane = t & 63;
  const int bh = blockIdx.x, b = bh >> 4, h = bh & 15;
  const int qt = 31 - blockIdx.y;                 // longest blocks first
  const int qbase = qt * 64 + w * 16;
  const int kq = lane >> 4, ncol = lane & 15;
  const int sw = (ncol & 7);                      // row&7 for all frag rows

  const __bf16* qp = q + (size_t)bh * 2048 * 64;
  const __bf16* kp = k + (size_t)bh * 2048 * 64;
  const __bf16* vp = vt + (size_t)bh * 64 * 2048;
  const float* tb = tbl + h * 2048;
  const float bconst = tb[2047] - FIXMAX;  // bucket-31 bias, fixed shift folded

  __bf16* Pw = &lPT[w][0];

  // Q B-fragment: lane holds Q[qbase+ncol][kq*8 + j (+32)]
  bf16x8 qf0 = *(const bf16x8*)&qp[(size_t)(qbase + ncol) * 64 + kq * 8];
  bf16x8 qf1 = *(const bf16x8*)&qp[(size_t)(qbase + ncol) * 64 + kq * 8 + 32];

  f32x4 O[4] = {};
  float lsum = 0.f;

  for (int jt = 0; jt <= qt; ++jt) {
    const int dt = qt - jt;
    const int rel = 4 * dt + w;
    __syncthreads();                  // prev-step PV reads of lK/lV complete
    // STAGE tile jt (single-buffered): 2 issues/thread cover all 64 rows
#pragma unroll
    for (int r = 0; r < 2; ++r) {
      int c = r * 256 + t;
      int row = c >> 3, cc = c & 7;
      int sc = cc ^ (row & 7);        // pre-swizzled source chunk
      gload16(kp + (size_t)(jt * 64 + row) * 64 + sc * 8,
              &lK[(r * 256 + w * 64) * 8]);
      gload16(vp + (size_t)row * 2048 + jt * 64 + sc * 8,
              &lV[(r * 256 + w * 64) * 8]);
    }
    if (dt < 3 && t < 128) {          // bias window only near the diagonal
      int rb = dt * 64 - 63 + t;
      lb[t] = tb[rb < 0 ? 0 : rb] - FIXMAX;
    }
    __syncthreads();                  // vmcnt drained: K/V/bias ready

    const bool useb = (dt >= 3);

    // S^T = K Q^T + (bias - FIXMAX) C-init; elem (fn,i): key=16fn+4kq+i,
    // qrow=ncol. P = exp2(S) directly (shift already folded into C-init).
    const int idxb = 63 + w * 16 + ncol - 4 * kq;
#pragma unroll
    for (int fn = 0; fn < 4; ++fn) {
      bf16x4 pb;
      if (fn <= rel) {
        f32x4 s;
        if (useb) {
          s = (f32x4){bconst, bconst, bconst, bconst};
        } else {
#pragma unroll
          for (int i = 0; i < 4; ++i) s[i] = lb[idxb - fn * 16 - i];
          if (fn == rel) {   // diagonal quarter: mask future keys
#pragma unroll
            for (int i = 0; i < 4; ++i)
              if (ncol - 4 * kq - i < 0) s[i] = -1e30f;
          }
        }
        int row = fn * 16 + ncol;
        bf16x8 kf0 = *(const bf16x8*)((const char*)lK + row * 128 + ((kq ^ sw) * 16));
        bf16x8 kf1 = *(const bf16x8*)((const char*)lK + row * 128 + (((4 + kq) ^ sw) * 16));
        s = mfma16(kf0, qf0, s);
        s = mfma16(kf1, qf1, s);
#pragma unroll
        for (int i = 0; i < 4; ++i) {
          float pe = exp2a(s[i]);
          lsum += pe;
          pb[i] = (__bf16)pe;
        }
      } else {
        pb = (bf16x4){(__bf16)0.f, (__bf16)0.f, (__bf16)0.f, (__bf16)0.f};
      }
      *(bf16x4*)((char*)Pw + ncol * 128 + ((32 * fn + 8 * kq) ^ (sw << 4))) = pb;
    }
    asm volatile("s_waitcnt lgkmcnt(0)" ::: "memory");
    __builtin_amdgcn_sched_barrier(0);

    // O += P V : A-frag P[qrow=ncol][key], B-frag V[key][d] from lV rows
    const int kf2max = (rel >= 2) ? 2 : 1;   // keys>=32 all zero if rel<2
    for (int kf2 = 0; kf2 < kf2max; ++kf2) {
      bf16x8 pf = *(const bf16x8*)((const char*)Pw + ncol * 128 +
                                   (((4 * kf2 + kq) ^ sw) * 16));
#pragma unroll
      for (int fd = 0; fd < 4; ++fd) {
        int vrow = fd * 16 + ncol;
        bf16x8 vf = *(const bf16x8*)((const char*)lV + vrow * 128 +
                                     (((4 * kf2 + kq) ^ sw) * 16));
        O[fd] = mfma16(pf, vf, O[fd]);
      }
    }
  }

  // epilogue: total row sums, then normalize rows 4kq+i
  lsum += __shfl_xor(lsum, 16);
  lsum += __shfl_xor(lsum, 32);
#pragma unroll
  for (int i = 0; i < 4; ++i) {
    float li = __shfl(lsum, 4 * kq + i);
    float rinv = 1.0f / li;
    int row = qbase + 4 * kq + i;
#pragma unroll
    for (int fd = 0; fd < 4; ++fd) {
      int col = h * 64 + fd * 16 + ncol;
      y[((size_t)(b * 2048 + row)) * 1024 + col] = (__bf16)(O[fd][i] * rinv);
    }
  }
}

// ---------------- launch ----------------

extern "C" void kernel_launch(void* const* d_in, const int* in_sizes, int n_in,
                              void* d_out, int out_size, void* d_ws, size_t ws_size,
                              hipStream_t stream) {
  const float* x = (const float*)d_in[0];
  const float* W_attn = (const float*)d_in[1];
  const float* b_attn = (const float*)d_in[2];
  const float* W_proj = (const float*)d_in[3];
  const float* b_proj = (const float*)d_in[4];
  const float* bias_table = (const float*)d_in[5];
  float* out = (float*)d_out;

  char* ws = (char*)d_ws;
  __bf16* xb   = (__bf16*)(ws + 0);          // 4096x1024           8 MB
  __bf16* WaT  = (__bf16*)(ws + 8388608);    // 3072x1024           6 MB
  __bf16* WpT  = (__bf16*)(ws + 14680064);   // 1024x1024           2 MB
  __bf16* qb   = (__bf16*)(ws + 16777216);   // [B,H,T,D]           8 MB
  __bf16* kb   = (__bf16*)(ws + 25165824);   // [B,H,T,D]           8 MB
  __bf16* vtb  = (__bf16*)(ws + 33554432);   // [B,H,D,T]           8 MB
  __bf16* yb   = (__bf16*)(ws + 41943040);   // [B,T,C]             8 MB
  float*  tbl  = (float*)(ws + 50331648);    // [H,T] bias*log2e  128 KB

  prep_k<<<8320, 256, 0, stream>>>(x, W_attn, W_proj, bias_table,
                                   xb, WaT, WpT, tbl);
  gemm_bf16<0><<<dim3(32, 24), 256, 0, stream>>>(xb, WaT, b_attn, nullptr,
                                                 qb, kb, vtb, 4096, 3072, 1024);
  attn_k<<<dim3(32, 32), 256, 0, stream>>>(qb, kb, vtb, tbl, yb);
  gemm_bf16<1><<<dim3(32, 8), 256, 0, stream>>>(yb, WpT, b_proj, out,
                                                nullptr, nullptr, nullptr,
                                                4096, 1024, 1024);
}